// Round 2
// baseline (1443.623 us; speedup 1.0000x reference)
//
#include <hip/hip_runtime.h>

#ifndef __has_builtin
#define __has_builtin(x) 0
#endif

typedef float v2 __attribute__((ext_vector_type(2)));

// ---- fast HW transcendentals (v_exp_f32 computes 2^x; v_rcp_f32) ----
__device__ __forceinline__ float fast_exp2(float x) {
#if __has_builtin(__builtin_amdgcn_exp2f)
  return __builtin_amdgcn_exp2f(x);
#else
  return exp2f(x);
#endif
}
__device__ __forceinline__ float fast_rcp(float x) {
#if __has_builtin(__builtin_amdgcn_rcpf)
  return __builtin_amdgcn_rcpf(x);
#else
  return 1.0f / x;
#endif
}

__device__ __forceinline__ v2 vfma(v2 a, v2 b, v2 c) {
  return __builtin_elementwise_fma(a, b, c);
}

namespace {
constexpr int kB = 131072;
constexpr int kSeq = 150;
constexpr int kD = 2;
constexpr int kH = 64;
constexpr int kPred = 150;
constexpr int kSteps = kPred - 1;            // 149
constexpr float kDt = 150.0f / 149.0f;       // linspace(0,150,150) spacing
constexpr float kC = 2.8853900817779268f;    // 2*log2(e)
constexpr float kClamp = 30.0f;              // exp2 arg clamp (sigma err <1e-9)
constexpr int kSplit = 4;                    // lanes per batch element
constexpr int kHper = kH / kSplit;           // 16 hidden units per lane
constexpr int kBlock = 256;
constexpr int kElemsPerBlock = kBlock / kSplit;  // 64
}  // namespace

// Butterfly exchange within each 4-lane quad via DPP quad_perm (pure VALU).
// xor1: perm(1,0,3,2) = 0xB1 ; xor2: perm(2,3,0,1) = 0x4E
template <int PAT>
__device__ __forceinline__ v2 dpp_swap(v2 v) {
  int lo = __builtin_amdgcn_update_dpp(0, __float_as_int(v.x), PAT, 0xF, 0xF, true);
  int hi = __builtin_amdgcn_update_dpp(0, __float_as_int(v.y), PAT, 0xF, 0xF, true);
  v2 r;
  r.x = __int_as_float(lo);
  r.y = __int_as_float(hi);
  return r;
}

// f(y) = tanh(y@W1+b1)@W2 + b2, folded:
//   tanh(q) = 1 - 2*rcp(1 + exp2(q*2log2e))
//   per-lane (16 of 64 hidden units), processed as 4 groups of 4 with a
//   SHARED reciprocal: r_i = (prod_{j!=i} s_j) * rcp(prod s_j), s = 1+e.
//   Packed (v_pk_*_f32) throughout: units in pairs, state/k's as v2.
__global__ __launch_bounds__(kBlock, 3) void ode_kernel(
    const float* __restrict__ x, const float* __restrict__ W1,
    const float* __restrict__ b1, const float* __restrict__ W2,
    const float* __restrict__ b2, float* __restrict__ out) {
  const int t = threadIdx.x;
  const int part = t & (kSplit - 1);
  const int j0 = part * kHper;

  // Weights live entirely in VGPRs as packed pairs; all indices are
  // compile-time after full unroll (runtime-indexed arrays -> scratch).
  v2 wx[kHper / 2], wy[kHper / 2], wb[kHper / 2], wz[kHper / 2], ww[kHper / 2];
#pragma unroll
  for (int i = 0; i < kHper / 2; ++i) {
    const int j = j0 + 2 * i;
    // W1 is (D,H) row-major; W2 is (H,D) row-major.
    wx[i].x = W1[j] * kC;
    wx[i].y = W1[j + 1] * kC;
    wy[i].x = W1[kH + j] * kC;
    wy[i].y = W1[kH + j + 1] * kC;
    wb[i].x = b1[j] * kC;
    wb[i].y = b1[j + 1] * kC;
    wz[i].x = -2.0f * W2[2 * j];
    wz[i].y = -2.0f * W2[2 * (j + 1)];
    ww[i].x = -2.0f * W2[2 * j + 1];
    ww[i].y = -2.0f * W2[2 * (j + 1) + 1];
  }
  // lane partial base: 0.25*b2[d] + sum_own_j W2[j][d]  (wz = -2*W2)
  v2 pb;
  pb.x = 0.25f * b2[0];
  pb.y = 0.25f * b2[1];
#pragma unroll
  for (int i = 0; i < kHper / 2; ++i) {
    pb.x = fmaf(-0.5f, wz[i].x + wz[i].y, pb.x);
    pb.y = fmaf(-0.5f, ww[i].x + ww[i].y, pb.y);
  }

  const long elem = (long)blockIdx.x * kElemsPerBlock + (t >> 2);
  const float* xp = x + elem * (long)(kSeq * kD) + (kSeq - 1) * kD;
  v2 y = *reinterpret_cast<const v2*>(xp);  // 8B-aligned (offset 298*4)
  float* op = out + elem * (long)(kPred * kD);

  auto feval = [&](v2 u) -> v2 {
    // 4 independent acc chains (ILP): d0/d1 x even/odd pair
    v2 acc0a, acc1a, acc0b, acc1b;
    acc0a.x = pb.x; acc0a.y = 0.0f;
    acc1a.x = pb.y; acc1a.y = 0.0f;
    acc0b.x = 0.0f; acc0b.y = 0.0f;
    acc1b.x = 0.0f; acc1b.y = 0.0f;
    v2 U0, U1;
    U0.x = u.x; U0.y = u.x;
    U1.x = u.y; U1.y = u.y;
#pragma unroll
    for (int g = 0; g < kHper / 4; ++g) {
      const int iA = 2 * g, iB = 2 * g + 1;
      v2 pA = vfma(U0, wx[iA], vfma(U1, wy[iA], wb[iA]));
      v2 pB = vfma(U0, wx[iB], vfma(U1, wy[iB], wb[iB]));
      pA = __builtin_elementwise_min(pA, (v2)kClamp);
      pB = __builtin_elementwise_min(pB, (v2)kClamp);
      v2 eA, eB;
      eA.x = fast_exp2(pA.x);
      eA.y = fast_exp2(pA.y);
      eB.x = fast_exp2(pB.x);
      eB.y = fast_exp2(pB.y);
      v2 sA = eA + 1.0f;
      v2 sB = eB + 1.0f;
      // shared reciprocal across the 4 sigmoids
      float mA = sA.x * sA.y;
      float mB = sB.x * sB.y;
      float R = fast_rcp(mA * mB);
      float tA = mB * R;  // = 1/mA
      float tB = mA * R;  // = 1/mB
      v2 rA = sA.yx * tA;  // {1/sA.x, 1/sA.y}
      v2 rB = sB.yx * tB;
      acc0a = vfma(rA, wz[iA], acc0a);
      acc1a = vfma(rA, ww[iA], acc1a);
      acc0b = vfma(rB, wz[iB], acc0b);
      acc1b = vfma(rB, ww[iB], acc1b);
    }
    v2 s0 = acc0a + acc0b;
    v2 s1 = acc1a + acc1b;
    v2 f;
    f.x = s0.x + s0.y;
    f.y = s1.x + s1.y;
    // 4-lane butterfly: every lane ends with the full 64-hidden sum
    // (bitwise identical across the quad: fp add is commutative).
    f = f + dpp_swap<0xB1>(f);
    f = f + dpp_swap<0x4E>(f);
    return f;
  };

  // previous even-index state (for paired float4 stores)
  v2 py = y;
  constexpr float DT = kDt, DT3 = kDt / 3.0f, DT8 = kDt / 8.0f;

  for (int s = 1; s <= kSteps; ++s) {
    v2 k1 = feval(y);
    v2 k2 = feval(vfma((v2)DT3, k1, y));
    v2 k3 = feval(vfma((v2)DT, k2, vfma((v2)(-DT3), k1, y)));
    v2 k4 = feval(vfma((v2)DT, (k1 - k2) + k3, y));
    y = vfma((v2)DT8, vfma((v2)3.0f, k2 + k3, k1) + k4, y);

    if (s & 1) {
      if (part == 0) {
        // write times (s-1, s) as one 16B store; offsets are 16B-aligned
        float4 v = make_float4(py.x, py.y, y.x, y.y);
        *reinterpret_cast<float4*>(op + (long)(s - 1) * 2) = v;
      }
    } else {
      py = y;
    }
  }
}

extern "C" void kernel_launch(void* const* d_in, const int* in_sizes, int n_in,
                              void* d_out, int out_size, void* d_ws,
                              size_t ws_size, hipStream_t stream) {
  const float* x = (const float*)d_in[0];
  const float* W1 = (const float*)d_in[1];
  const float* b1 = (const float*)d_in[2];
  const float* W2 = (const float*)d_in[3];
  const float* b2 = (const float*)d_in[4];
  float* out = (float*)d_out;

  dim3 grid(kB * kSplit / kBlock);  // 8192 blocks, 4 lanes per element
  dim3 block(kBlock);
  hipLaunchKernelGGL(ode_kernel, grid, block, 0, stream, x, W1, b1, W2, b2,
                     out);
}